// Round 2
// baseline (1257.803 us; speedup 1.0000x reference)
//
#include <hip/hip_runtime.h>

typedef _Float16 f16;
typedef _Float16 f16x8 __attribute__((ext_vector_type(8)));
typedef float f32x4 __attribute__((ext_vector_type(4)));

#define NBATCH 16
#define NH 256
#define NW 256
#define NC 32
#define NK 5

#define NCHUNK 16
#define CHW 16            // valid cols per chunk
#define G 16              // rows per exchange period
#define HALO 32           // 2*G
#define CW 80             // CHW + 2*HALO computed cols
#define NTHREADS 320      // 5 waves = 5 m-tiles of 16
#define XROWS 84          // CW + 2 pad rows each side
#define XSTR 40           // f16 row stride: 80 B = 20 banks (2-way only, free)
#define NBLOCKS (NBATCH * NCHUNK)   // 256 WGs <= 256 CUs: co-resident

__device__ __forceinline__ void grid_barrier(unsigned* bar, unsigned& my_gen) {
  __threadfence();
  __syncthreads();
  if (threadIdx.x == 0) {
    if (atomicAdd(&bar[0], 1u) == NBLOCKS - 1) {
      atomicExch(&bar[0], 0u);
      __threadfence();
      atomicAdd(&bar[1], 1u);
    } else {
      while (atomicAdd(&bar[1], 0u) == my_gen) __builtin_amdgcn_s_sleep(4);
    }
  }
  __syncthreads();
  __threadfence();
  my_gen += 1;
}

__global__ __launch_bounds__(NTHREADS, 1)
void mvcnn_down(const float* __restrict__ in, const float* __restrict__ wt,
                const float* __restrict__ bias, float* __restrict__ out,
                unsigned* __restrict__ bar, f16* __restrict__ exch) {
  __shared__ __align__(16) f16 xpad[2][XROWS * XSTR];  // 2 x 6720 B

  const int b     = blockIdx.x >> 4;
  const int chunk = blockIdx.x & 15;
  const int base  = chunk * CHW - HALO;  // global col of local col 0

  const int t    = threadIdx.x;
  const int lane = t & 63;
  const int wv   = t >> 6;        // wave id == m-tile
  const int n16  = lane & 15;
  const int q    = lane >> 4;

  // ---- resident weight B-fragments: B_tap[k=q*8+j][n=n16], o = nt*16+n16
  f16x8 bfrag[NK][2];
  #pragma unroll
  for (int tap = 0; tap < NK; ++tap) {
    #pragma unroll
    for (int nt = 0; nt < 2; ++nt) {
      f16x8 f;
      #pragma unroll
      for (int j = 0; j < 8; ++j)
        f[j] = (f16)wt[((q * 8 + j) * NK + tap) * NC + nt * 16 + n16];
      bfrag[tap][nt] = f;
    }
  }
  const float bias0 = bias[n16];
  const float bias1 = bias[16 + n16];

  // zero both xpad buffers (pad rows 0,1,82,83 stay zero forever)
  for (int i = t; i < 2 * XROWS * XSTR; i += NTHREADS) (&xpad[0][0])[i] = (f16)0.f;

  const float* inb  = in  + (size_t)b * NH * NW * NC;
  float*       outb = out + (size_t)b * NH * NW * NC;

  const int wo0 = wv * 16 + q * 4;   // C/D rows wo0..wo0+3 (row = q*4+reg)
  const int gc0 = base + wo0;
  const int arow = wv * 16 + n16;    // A-operand row (m = lane&15)
  unsigned my_gen = 0;

  float pf0[8], pf1[8];
  auto load_in_row = [&](int h1, float (&pf)[8]) {
    const float* rp = inb + (size_t)h1 * NW * NC;
    #pragma unroll
    for (int r = 0; r < 4; ++r) {
      int gc = gc0 + r;
      bool ok = (unsigned)gc < NW;
      pf[2 * r]     = ok ? rp[gc * NC + n16]      : 0.f;
      pf[2 * r + 1] = ok ? rp[gc * NC + 16 + n16] : 0.f;
    }
  };

  // ---- stage row 0: x_0 = in_0 (r_{-1}=0), full window, out-of-image -> 0
  {
    #pragma unroll
    for (int r = 0; r < 4; ++r) {
      int gc = gc0 + r;
      bool img = (unsigned)gc < NW;
      f16* xw = &xpad[0][(wo0 + r + 2) * XSTR];
      xw[n16]      = img ? (f16)inb[gc * NC + n16]      : (f16)0.f;
      xw[16 + n16] = img ? (f16)inb[gc * NC + 16 + n16] : (f16)0.f;
    }
  }
  load_in_row(1, pf0);   // consumed at epilogue h=0
  load_in_row(2, pf1);   // consumed at epilogue h=1
  __syncthreads();

  auto body = [&](const int h, float (&pf)[8], f16* xp_cur, f16* xp_nxt) {
    // ---- halo repair every G rows: x_h[halo] = in_h + published r_{h-1}
    if ((h & (G - 1)) == 0 && h > 0) {
      grid_barrier(bar, my_gen);
      if (wv != 2) {
        const float* rp = inb + (size_t)h * NW * NC;
        #pragma unroll
        for (int r = 0; r < 4; ++r) {
          int gc = gc0 + r;
          if ((unsigned)gc < NW) {
            const f16* ep = exch + ((size_t)b * NW + gc) * NC;
            float x0 = rp[gc * NC + n16]      + (float)ep[n16];
            float x1 = rp[gc * NC + 16 + n16] + (float)ep[16 + n16];
            f16* xw = xp_cur + (wo0 + r + 2) * XSTR;
            xw[n16]      = (f16)x0;
            xw[16 + n16] = (f16)x1;
          }
        }
      }
      __syncthreads();
    }

    // ---- MFMA: y[w][o] = sum_{tap,c} x[w+tap-2][c] * W_tap[c][o]
    f32x4 acc0 = {0.f, 0.f, 0.f, 0.f};
    f32x4 acc1 = {0.f, 0.f, 0.f, 0.f};
    #pragma unroll
    for (int tap = 0; tap < NK; ++tap) {
      f16x8 af = *(const f16x8*)(xp_cur + (arow + tap) * XSTR + q * 8);
      acc0 = __builtin_amdgcn_mfma_f32_16x16x32_f16(af, bfrag[tap][0], acc0, 0, 0, 0);
      acc1 = __builtin_amdgcn_mfma_f32_16x16x32_f16(af, bfrag[tap][1], acc1, 0, 0, 0);
    }

    // ---- epilogue: r = relu(y+b); store out (valid wave only);
    //      publish r before sync rows; stage x_{h+1} into other buffer
    const bool publish = ((h & (G - 1)) == G - 1) && (h != NH - 1);
    float* orow = outb + (size_t)h * NW * NC;
    #pragma unroll
    for (int r = 0; r < 4; ++r) {
      float y0 = acc0[r] + bias0; y0 = y0 > 0.f ? y0 : 0.f;
      float y1 = acc1[r] + bias1; y1 = y1 > 0.f ? y1 : 0.f;
      int wo = wo0 + r;
      int gc = gc0 + r;
      bool img = (unsigned)gc < NW;
      if (wv == 2) {                 // local [32,48) == valid chunk
        orow[gc * NC + n16]      = y0;
        orow[gc * NC + 16 + n16] = y1;
        if (publish) {
          f16* ep = exch + ((size_t)b * NW + gc) * NC;
          ep[n16]      = (f16)y0;
          ep[16 + n16] = (f16)y1;
        }
      }
      if (h < NH - 1) {
        f16* xw = xp_nxt + (wo + 2) * XSTR;
        xw[n16]      = img ? (f16)(pf[2 * r]     + y0) : (f16)0.f;
        xw[16 + n16] = img ? (f16)(pf[2 * r + 1] + y1) : (f16)0.f;
      }
    }
    if (h + 3 < NH) load_in_row(h + 3, pf);  // lands ~2 rows of latency ahead
    __syncthreads();
  };

  f16* xA = &xpad[0][0];
  f16* xB = &xpad[1][0];
  for (int h = 0; h < NH; h += 2) {
    body(h,     pf0, xA, xB);
    body(h + 1, pf1, xB, xA);
  }
}

extern "C" void kernel_launch(void* const* d_in, const int* in_sizes, int n_in,
                              void* d_out, int out_size, void* d_ws, size_t ws_size,
                              hipStream_t stream) {
  const float* in   = (const float*)d_in[0];
  const float* wt   = (const float*)d_in[1];
  const float* bias = (const float*)d_in[2];
  float* out = (float*)d_out;

  unsigned* bar = (unsigned*)d_ws;                    // [0]=arrive, [1]=gen
  f16* exch = (f16*)((char*)d_ws + 1024);             // 16*256*32 f16 = 512 KB

  // zero barrier state (d_ws is poisoned 0xAA before every launch)
  hipMemsetAsync(d_ws, 0, 1024, stream);
  hipLaunchKernelGGL(mvcnn_down, dim3(NBLOCKS), dim3(NTHREADS), 0, stream,
                     in, wt, bias, out, bar, exch);
}

// Round 4
// 610.229 us; speedup vs baseline: 2.0612x; 2.0612x over previous
//
#include <hip/hip_runtime.h>

typedef _Float16 f16;
typedef _Float16 f16x2 __attribute__((ext_vector_type(2)));
typedef _Float16 f16x8 __attribute__((ext_vector_type(8)));
typedef float f32x4 __attribute__((ext_vector_type(4)));

#define NB 16
#define NH 256
#define NW 256
#define NC 32
#define NK 5

// xpad: conv window rows (w+tap), 2 zero-pad rows each side, double-buffered.
// Row stride 40 f16 = 80 B; channel order within a row is PERMUTED:
// position p holds channel (p>>1) + (p&1)*16, so each lane's epilogue pair
// (ch n16, ch n16+16) is one aligned b32 write -> conflict-free banks.
#define XSTR 40
#define XROWS 260

__device__ __forceinline__ void lds_barrier() {
  // LDS is the only cross-wave state: wait lgkm only, let global loads/stores
  // (input prefetch, output writes) stay in flight across the barrier.
  asm volatile("s_waitcnt lgkmcnt(0)\n\ts_barrier" ::: "memory");
}

__global__ __launch_bounds__(1024, 4)
void mvcnn_down(const float* __restrict__ in, const float* __restrict__ wt,
                const float* __restrict__ bias, float* __restrict__ out) {
  __shared__ __align__(16) f16 xpad[2][XROWS * XSTR];  // 2 x 20800 B

  const int b    = blockIdx.x;
  const int t    = threadIdx.x;
  const int lane = t & 63;
  const int wv   = t >> 6;      // wave id == m-tile (cols wv*16..wv*16+15)
  const int n16  = lane & 15;
  const int q    = lane >> 4;

  // ---- resident weight B-fragments, k-permuted to match xpad layout ----
  // lane holds k-positions p = q*8+j  ->  channel c = q*4 + (j>>1) + (j&1)*16
  f16x8 bfrag[NK][2];
  #pragma unroll
  for (int tap = 0; tap < NK; ++tap) {
    #pragma unroll
    for (int nt = 0; nt < 2; ++nt) {
      f16x8 f;
      #pragma unroll
      for (int j = 0; j < 8; ++j) {
        int c = q * 4 + (j >> 1) + (j & 1) * 16;
        f[j] = (f16)wt[(c * NK + tap) * NC + nt * 16 + n16];
      }
      bfrag[tap][nt] = f;
    }
  }
  const float bias0 = bias[n16];
  const float bias1 = bias[16 + n16];

  // zero both buffers (pad rows 0,1,258,259 stay zero forever)
  for (int i = t; i < 2 * XROWS * XSTR; i += 1024) (&xpad[0][0])[i] = (f16)0.f;
  // BARRIER REQUIRED: zero loop is thread-strided across ALL rows; staging
  // below writes per-wave rows. Without this, slow waves' zeros clobber
  // fast waves' staged x_0 (round-3 failure).
  __syncthreads();

  const float* inb  = in  + (size_t)b * NH * NW * NC;
  float*       outb = out + (size_t)b * NH * NW * NC;

  const int wo0  = wv * 16 + q * 4;  // C/D rows wo0..wo0+3 (row = q*4+reg)
  const int arow = wv * 16 + n16;    // A-operand row (m = lane&15)

  float pf0[8], pf1[8];
  auto load_in_row = [&](int h1, float (&pf)[8]) {
    const float* rp = inb + (size_t)h1 * NW * NC;
    #pragma unroll
    for (int r = 0; r < 4; ++r) {
      int wo = wo0 + r;
      pf[2 * r]     = rp[wo * NC + n16];
      pf[2 * r + 1] = rp[wo * NC + 16 + n16];
    }
  };

  // ---- stage row 0: x_0 = in_0 (r_{-1}=0) in permuted layout ----
  #pragma unroll
  for (int r = 0; r < 4; ++r) {
    int wo = wo0 + r;
    f16x2 v;
    v[0] = (f16)inb[wo * NC + n16];
    v[1] = (f16)inb[wo * NC + 16 + n16];
    *(f16x2*)(&xpad[0][(wo + 2) * XSTR + 2 * n16]) = v;
  }
  load_in_row(1, pf0);   // consumed at epilogue h=0
  load_in_row(2, pf1);   // consumed at epilogue h=1
  __syncthreads();

  auto body = [&](const int h, float (&pf)[8], const f16* xp_cur, f16* xp_nxt) {
    // ---- MFMA: y[w][o] = sum_{tap,kpos} x[w+tap-2][kpos] * W[kpos][tap][o]
    f32x4 acc0 = {0.f, 0.f, 0.f, 0.f};
    f32x4 acc1 = {0.f, 0.f, 0.f, 0.f};
    #pragma unroll
    for (int tap = 0; tap < NK; ++tap) {
      f16x8 af = *(const f16x8*)(xp_cur + (arow + tap) * XSTR + q * 8);
      acc0 = __builtin_amdgcn_mfma_f32_16x16x32_f16(af, bfrag[tap][0], acc0, 0, 0, 0);
      acc1 = __builtin_amdgcn_mfma_f32_16x16x32_f16(af, bfrag[tap][1], acc1, 0, 0, 0);
    }

    // ---- epilogue: r = relu(y+b); store out; x_{h+1} = r + in_{h+1} ----
    float* orow = outb + (size_t)h * NW * NC;
    #pragma unroll
    for (int r = 0; r < 4; ++r) {
      float y0 = acc0[r] + bias0; y0 = y0 > 0.f ? y0 : 0.f;
      float y1 = acc1[r] + bias1; y1 = y1 > 0.f ? y1 : 0.f;
      int wo = wo0 + r;
      orow[wo * NC + n16]      = y0;
      orow[wo * NC + 16 + n16] = y1;
      if (h < NH - 1) {
        f16x2 v;
        v[0] = (f16)(pf[2 * r]     + y0);
        v[1] = (f16)(pf[2 * r + 1] + y1);
        *(f16x2*)(&xp_nxt[(wo + 2) * XSTR + 2 * n16]) = v;
      }
    }
    if (h + 3 < NH) load_in_row(h + 3, pf);  // ~2 rows of latency slack
    lds_barrier();
  };

  const f16* xA = &xpad[0][0];
  f16* xB = &xpad[1][0];
  for (int h = 0; h < NH; h += 2) {
    body(h,     pf0, xA, xB);
    body(h + 1, pf1, xB, (f16*)xA);
  }
}

extern "C" void kernel_launch(void* const* d_in, const int* in_sizes, int n_in,
                              void* d_out, int out_size, void* d_ws, size_t ws_size,
                              hipStream_t stream) {
  const float* in   = (const float*)d_in[0];
  const float* wt   = (const float*)d_in[1];
  const float* bias = (const float*)d_in[2];
  float* out = (float*)d_out;
  hipLaunchKernelGGL(mvcnn_down, dim3(NB), dim3(1024), 0, stream,
                     in, wt, bias, out);
}